// Round 5
// baseline (304.634 us; speedup 1.0000x reference)
//
#include <hip/hip_runtime.h>

typedef unsigned short u16;
typedef unsigned int u32;
typedef __bf16 bf16x8 __attribute__((ext_vector_type(8)));
typedef float floatx4 __attribute__((ext_vector_type(4)));

// B=4, S=1024, DIM=2048, HQ=16, HKV=4, HD=128, G=4
__device__ __forceinline__ u16 f2bf(float x) {
  union { float f; u32 u; } v; v.f = x;
  u32 r = v.u + 0x7fffu + ((v.u >> 16) & 1u);   // RNE
  return (u16)(r >> 16);
}
__device__ __forceinline__ float bf2f(u16 x) {
  union { float f; u32 u; } v; v.u = ((u32)x) << 16;
  return v.f;
}

// async global->LDS, 16B per lane. LDS dest must be wave-uniform base + lane*16.
__device__ __forceinline__ void gl_lds16(const u16* g, u16* l) {
  __builtin_amdgcn_global_load_lds((const __attribute__((address_space(1))) void*)g,
                                   (__attribute__((address_space(3))) void*)l, 16, 0, 0);
}

// ---------------- fused f32 -> bf16 conversion of all 5 tensors ----------------
__global__ __launch_bounds__(256) void cvt_all(const float* __restrict__ x,
                                               const float* __restrict__ wq,
                                               const float* __restrict__ wk,
                                               const float* __restrict__ wv,
                                               const float* __restrict__ wo,
                                               u16* __restrict__ xb, u16* __restrict__ wqb,
                                               u16* __restrict__ wkb, u16* __restrict__ wvb,
                                               u16* __restrict__ wob) {
  int i = blockIdx.x * 256 + threadIdx.x;  // float4 index
  const float* s; u16* d; int off;
  if (i < 2097152)      { s = x;  d = xb;  off = 0; }
  else if (i < 3145728) { s = wq; d = wqb; off = 2097152; }
  else if (i < 3407872) { s = wk; d = wkb; off = 3145728; }
  else if (i < 3670016) { s = wv; d = wvb; off = 3407872; }
  else                  { s = wo; d = wob; off = 3670016; }
  i -= off;
  float4 v = ((const float4*)s)[i];
  uint2 o;
  o.x = (u32)f2bf(v.x) | ((u32)f2bf(v.y) << 16);
  o.y = (u32)f2bf(v.z) | ((u32)f2bf(v.w) << 16);
  ((uint2*)d)[i] = o;
}

// ---------------- RoPE in-place on q and k in one launch ----------------
__global__ __launch_bounds__(256) void rope_both(u16* __restrict__ qb, u16* __restrict__ kb,
                                                 const float* __restrict__ fr) {
  int idx = blockIdx.x * 256 + threadIdx.x;
  u16* t; int lgH; float scale;
  if (idx < 4194304) { t = qb; lgH = 4; scale = 0.08838834764831845f; }
  else               { t = kb; lgH = 2; scale = 1.0f; idx -= 4194304; }
  int p = idx & 63;
  int bsh = idx >> 6;
  int s = (bsh >> lgH) & 1023;
  float th = fr[s * 64 + p];
  float sn, cs;
  sincosf(th, &sn, &cs);
  u32* base = (u32*)(t + (size_t)bsh * 128 + p * 2);
  u32 pr = *base;
  float e = bf2f((u16)(pr & 0xffffu));
  float o = bf2f((u16)(pr >> 16));
  u16 re = f2bf((e * cs - o * sn) * scale);
  u16 im = f2bf((e * sn + o * cs) * scale);
  *base = (u32)re | ((u32)im << 16);
}

// ---------------- shared GEMM core: 128x128 tile, K=2048, BK=64, async staging --
// LDS layout XOR-swizzled: LDS(row, chunk) holds global(row, chunk ^ (row&7)),
// chunk = 8 u16 = 16 B. Kills the 16-way ds_read_b128 bank conflicts of the
// naive row-stride-128B layout (row&7 spreads reads across all 8 chunk slots).
__device__ __forceinline__ void gemm_core(const u16* __restrict__ A, const u16* __restrict__ Bw,
                                          u16* sA, u16* sB, int m0, int n0,
                                          floatx4 acc[4][4]) {
  const int tid = threadIdx.x;
  const int wave = tid >> 6, lane = tid & 63;
  const int quad = lane >> 4, l16 = lane & 15;
  const int wm = (wave >> 1) * 64, wn = (wave & 1) * 64;
  const int srow = wave * 8 + (lane >> 3);
  // swizzled global source chunk for this lane's LDS slot (chunk = lane&7, row&7 = (lane>>3)&7)
  const int scol = (((lane & 7) ^ ((lane >> 3) & 7)) * 8);
  const int lds_off = wave * 512 + lane * 8;
  const int swA = (l16 & 7);  // read-side swizzle key (row&7 for MFMA fragment rows)
  for (int k0 = 0; k0 < 2048; k0 += 64) {
    __syncthreads();
    #pragma unroll
    for (int c = 0; c < 4; c++) {
      gl_lds16(A + (size_t)(m0 + c * 32 + srow) * 2048 + k0 + scol, sA + c * 2048 + lds_off);
      gl_lds16(Bw + (size_t)(n0 + c * 32 + srow) * 2048 + k0 + scol, sB + c * 2048 + lds_off);
    }
    __syncthreads();
    #pragma unroll
    for (int ks = 0; ks < 64; ks += 32) {
      const int pc = ((((ks >> 3) + quad) ^ swA) << 3);  // physical chunk*8
      bf16x8 af[4], bw[4];
      #pragma unroll
      for (int i = 0; i < 4; i++)
        af[i] = *(const bf16x8*)&sA[(wm + i * 16 + l16) * 64 + pc];
      #pragma unroll
      for (int j = 0; j < 4; j++)
        bw[j] = *(const bf16x8*)&sB[(wn + j * 16 + l16) * 64 + pc];
      #pragma unroll
      for (int i = 0; i < 4; i++)
        #pragma unroll
        for (int j = 0; j < 4; j++)
          acc[i][j] = __builtin_amdgcn_mfma_f32_16x16x32_bf16(af[i], bw[j], acc[i][j], 0, 0, 0);
    }
  }
}

// ---------------- fused QKV projection GEMM ----------------
__global__ __launch_bounds__(256, 2) void gemm_qkv(const u16* __restrict__ xb,
                                                   const u16* __restrict__ wqb,
                                                   const u16* __restrict__ wkb,
                                                   const u16* __restrict__ wvb,
                                                   u16* __restrict__ qb, u16* __restrict__ kb,
                                                   u16* __restrict__ vtb) {
  __shared__ __align__(16) u16 sA[128 * 64];
  __shared__ __align__(16) u16 sB[128 * 64];
  const int by = blockIdx.y;
  const u16* Bw; int n0, mode;
  if (by < 16)      { Bw = wqb; n0 = by * 128;        mode = 0; }
  else if (by < 20) { Bw = wkb; n0 = (by - 16) * 128; mode = 1; }
  else              { Bw = wvb; n0 = (by - 20) * 128; mode = 2; }
  const int m0 = blockIdx.x * 128;
  floatx4 acc[4][4] = {};
  gemm_core(xb, Bw, sA, sB, m0, n0, acc);
  const int tid = threadIdx.x;
  const int wave = tid >> 6, lane = tid & 63;
  const int quad = lane >> 4, l16 = lane & 15;
  const int wm = (wave >> 1) * 64, wn = (wave & 1) * 64;
  #pragma unroll
  for (int i = 0; i < 4; i++) {
    #pragma unroll
    for (int j = 0; j < 4; j++) {
      const int row0 = m0 + wm + i * 16 + quad * 4;
      const int col = n0 + wn + j * 16 + l16;
      #pragma unroll
      for (int r = 0; r < 4; r++) {
        int m = row0 + r;
        u16 val = f2bf(acc[i][j][r]);
        if (mode == 0) {
          qb[(size_t)m * 2048 + col] = val;
        } else if (mode == 1) {
          kb[(size_t)m * 512 + col] = val;
        } else {
          int b = m >> 10, sI = m & 1023, kvh = col >> 7, hd = col & 127;
          vtb[((size_t)((b * 4 + kvh) * 128 + hd)) * 1024 + sI] = val;
        }
      }
    }
  }
}

// ---------------- output projection GEMM (fp32 out) ----------------
__global__ __launch_bounds__(256, 2) void gemm_out(const u16* __restrict__ ob,
                                                   const u16* __restrict__ wob,
                                                   float* __restrict__ Cf) {
  __shared__ __align__(16) u16 sA[128 * 64];
  __shared__ __align__(16) u16 sB[128 * 64];
  const int m0 = blockIdx.x * 128, n0 = blockIdx.y * 128;
  floatx4 acc[4][4] = {};
  gemm_core(ob, wob, sA, sB, m0, n0, acc);
  const int tid = threadIdx.x;
  const int wave = tid >> 6, lane = tid & 63;
  const int quad = lane >> 4, l16 = lane & 15;
  const int wm = (wave >> 1) * 64, wn = (wave & 1) * 64;
  #pragma unroll
  for (int i = 0; i < 4; i++) {
    #pragma unroll
    for (int j = 0; j < 4; j++) {
      const int row0 = m0 + wm + i * 16 + quad * 4;
      const int col = n0 + wn + j * 16 + l16;
      #pragma unroll
      for (int r = 0; r < 4; r++)
        Cf[(size_t)(row0 + r) * 2048 + col] = acc[i][j][r];
    }
  }
}

// ---------------- flash attention (no-max softmax, S^T form, paired balance) ----
// Per-tile software pipeline: K 1-deep ping-pong prefetch (next hd-slice / next
// tile's slice 0 issued before current MFMAs); V half 0 issued before QK, half 1
// after QK -> load latency hidden under MFMA + softmax instead of serialized.
__device__ __forceinline__ void attn_chunk(const u16* __restrict__ qbaseHead,
                                           const u16* __restrict__ kbase,
                                           const u16* __restrict__ vbase,
                                           int qr0, int kt_begin, int kt_end,
                                           u16* myP, floatx4 (&o_acc)[2][8],
                                           float (&l_part)[2], int quad, int l16) {
  const floatx4 vzero = {0.f, 0.f, 0.f, 0.f};
  #pragma unroll
  for (int i = 0; i < 2; i++) {
    l_part[i] = 0.f;
    #pragma unroll
    for (int j = 0; j < 8; j++) o_acc[i][j] = vzero;
  }
  // Q B-fragments in registers: rows qr0+i*16+l16, k = ks*32+quad*8
  bf16x8 aq[2][4];
  #pragma unroll
  for (int i = 0; i < 2; i++)
    #pragma unroll
    for (int ks = 0; ks < 4; ks++)
      aq[i][ks] = *(const bf16x8*)(qbaseHead + (size_t)(qr0 + i * 16 + l16) * 2048 + ks * 32 + quad * 8);

  // K pipeline prologue: slice (kt_begin, ks=0) into bk[0]
  bf16x8 bk[2][4];
  #pragma unroll
  for (int j = 0; j < 4; j++)
    bk[0][j] = *(const bf16x8*)(kbase + (size_t)(kt_begin * 64 + j * 16 + l16) * 512 + quad * 8);

  for (int kt = kt_begin; kt < kt_end; kt++) {
    const int t0 = kt * 64;
    const int t0n = (kt + 1 < kt_end) ? t0 + 64 : t0;  // clamp: last-iter prefetch unused
    floatx4 s_acc[4][2];
    #pragma unroll
    for (int j = 0; j < 4; j++)
      #pragma unroll
      for (int i = 0; i < 2; i++) s_acc[j][i] = vzero;
    // V half 0 in flight during QK
    bf16x8 bv[2][8];
    #pragma unroll
    for (int j2 = 0; j2 < 8; j2++)
      bv[0][j2] = *(const bf16x8*)(vbase + (size_t)(j2 * 16 + l16) * 1024 + t0 + quad * 8);
    // ---- S^T = K Q^T with 1-deep K prefetch ----
    #pragma unroll
    for (int ks = 0; ks < 4; ks++) {
      const int nks = (ks + 1) & 3;
      const int nt0 = (ks == 3) ? t0n : t0;
      #pragma unroll
      for (int j = 0; j < 4; j++)
        bk[(ks + 1) & 1][j] =
            *(const bf16x8*)(kbase + (size_t)(nt0 + j * 16 + l16) * 512 + nks * 32 + quad * 8);
      #pragma unroll
      for (int j = 0; j < 4; j++)
        #pragma unroll
        for (int i = 0; i < 2; i++)
          s_acc[j][i] = __builtin_amdgcn_mfma_f32_16x16x32_bf16(bk[ks & 1][j], aq[i][ks], s_acc[j][i], 0, 0, 0);
    }
    // V half 1 in flight during softmax
    #pragma unroll
    for (int j2 = 0; j2 < 8; j2++)
      bv[1][j2] = *(const bf16x8*)(vbase + (size_t)(j2 * 16 + l16) * 1024 + t0 + 32 + quad * 8);
    // ---- no-max softmax: p = exp(s) (scale folded into Q), causal mask ----
    // lane holds qrow = qr0+i*16+l16, keys t0+j*16+quad*4+{0..3}
    #pragma unroll
    for (int i = 0; i < 2; i++) {
      const int qrow = qr0 + i * 16 + l16;
      #pragma unroll
      for (int j = 0; j < 4; j++) {
        const int key0 = t0 + j * 16 + quad * 4;
        float e0 = (key0 + 0 <= qrow) ? __expf(s_acc[j][i][0]) : 0.f;
        float e1 = (key0 + 1 <= qrow) ? __expf(s_acc[j][i][1]) : 0.f;
        float e2 = (key0 + 2 <= qrow) ? __expf(s_acc[j][i][2]) : 0.f;
        float e3 = (key0 + 3 <= qrow) ? __expf(s_acc[j][i][3]) : 0.f;
        l_part[i] += (e0 + e1) + (e2 + e3);
        uint2 w;
        w.x = (u32)f2bf(e0) | ((u32)f2bf(e1) << 16);
        w.y = (u32)f2bf(e2) | ((u32)f2bf(e3) << 16);
        *(uint2*)&myP[(i * 16 + l16) * 68 + j * 16 + quad * 4] = w;  // ds_write_b64
      }
    }
    // ---- O += P V : A = P[qrow][key] (b128 reads), B = V^T rows ----
    #pragma unroll
    for (int ks2 = 0; ks2 < 2; ks2++) {
      bf16x8 ap[2];
      #pragma unroll
      for (int i = 0; i < 2; i++)
        ap[i] = *(const bf16x8*)&myP[(i * 16 + l16) * 68 + ks2 * 32 + quad * 8];
      #pragma unroll
      for (int i = 0; i < 2; i++)
        #pragma unroll
        for (int j2 = 0; j2 < 8; j2++)
          o_acc[i][j2] = __builtin_amdgcn_mfma_f32_16x16x32_bf16(ap[i], bv[ks2][j2], o_acc[i][j2], 0, 0, 0);
    }
  }
}

__device__ __forceinline__ void store_out(u16* __restrict__ obaseHead, int qr0,
                                          floatx4 (&o_acc)[2][8], float (&l_part)[2],
                                          int quad, int l16) {
  #pragma unroll
  for (int i = 0; i < 2; i++) {
    float lr = l_part[i];
    lr += __shfl_xor(lr, 16);
    lr += __shfl_xor(lr, 32);
    // lane with l16=x (quad 0) now holds row total for qrow i*16+x
    #pragma unroll
    for (int r = 0; r < 4; r++) {
      const float inv = 1.f / __shfl(lr, quad * 4 + r);
      const int row = qr0 + i * 16 + quad * 4 + r;
      #pragma unroll
      for (int j = 0; j < 8; j++)
        obaseHead[(size_t)row * 2048 + j * 16 + l16] = f2bf(o_acc[i][j][r] * inv);
    }
  }
}

// grid 512: head = bi&63 (XCD-local K/V), sub = bi>>6; 4 waves = 2 (A,B) pairs.
// Pair pr handles chunks (p, 31-p); A computes first tA key-tiles of long chunk,
// B computes short chunk fully + rest of long chunk; partials are additive
// (no-max softmax) -> combine via LDS.
__global__ __launch_bounds__(256, 2) void flash_attn(const u16* __restrict__ q,
                                                     const u16* __restrict__ k,
                                                     const u16* __restrict__ vt,
                                                     u16* __restrict__ o) {
  __shared__ __align__(16) char smem[52224];  // 4*4352 P + 2*(16896 O + 512 L)
  const int tid = threadIdx.x;
  const int wave = tid >> 6, lane = tid & 63;
  const int quad = lane >> 4, l16 = lane & 15;
  const int pr = wave >> 1, role = wave & 1;  // role 0 = A (partial), 1 = B
  const int bi = blockIdx.x;
  const int h = bi & 63;                      // b*16 + hq
  const int b = h >> 4, hq = h & 15, kv = (hq >> 2);
  const int pair = (bi >> 6) * 2 + pr;        // 0..15
  const int p = pair, qc = 31 - pair;
  const int Tp = (32 * p + 31) / 64 + 1, Tq = (32 * qc + 31) / 64 + 1;
  const int tA = (Tp + Tq) >> 1;
  u16* myP = (u16*)(smem + wave * 4352);
  float* ldsO = (float*)(smem + 17408 + pr * 17408);
  float* ldsL = (float*)(smem + 17408 + pr * 17408 + 16896);

  const u16* qbaseHead = q + (size_t)b * 2097152 + hq * 128;
  const u16* kbase = k + (size_t)b * 524288 + kv * 128;
  const u16* vbase = vt + (size_t)(b * 4 + kv) * 131072;
  u16* obaseHead = o + (size_t)b * 2097152 + hq * 128;

  floatx4 o_acc[2][8];
  float l_part[2];
  if (role == 0) {
    attn_chunk(qbaseHead, kbase, vbase, qc * 32, 0, tA, myP, o_acc, l_part, quad, l16);
    #pragma unroll
    for (int i = 0; i < 2; i++) {
      ldsL[i * 64 + lane] = l_part[i];
      #pragma unroll
      for (int j = 0; j < 8; j++)
        #pragma unroll
        for (int r = 0; r < 4; r++)
          ldsO[(i * 16 + quad * 4 + r) * 132 + j * 16 + l16] = o_acc[i][j][r];
    }
    __syncthreads();
  } else {
    attn_chunk(qbaseHead, kbase, vbase, p * 32, 0, Tp, myP, o_acc, l_part, quad, l16);
    store_out(obaseHead, p * 32, o_acc, l_part, quad, l16);
    attn_chunk(qbaseHead, kbase, vbase, qc * 32, tA, Tq, myP, o_acc, l_part, quad, l16);
    __syncthreads();
    #pragma unroll
    for (int i = 0; i < 2; i++) {
      l_part[i] += ldsL[i * 64 + lane];
      #pragma unroll
      for (int j = 0; j < 8; j++)
        #pragma unroll
        for (int r = 0; r < 4; r++)
          o_acc[i][j][r] += ldsO[(i * 16 + quad * 4 + r) * 132 + j * 16 + l16];
    }
    store_out(obaseHead, qc * 32, o_acc, l_part, quad, l16);
  }
}

extern "C" void kernel_launch(void* const* d_in, const int* in_sizes, int n_in,
                              void* d_out, int out_size, void* d_ws, size_t ws_size,
                              hipStream_t stream) {
  const float* x  = (const float*)d_in[0];
  const float* fr = (const float*)d_in[2];
  const float* wq = (const float*)d_in[4];
  const float* wk = (const float*)d_in[5];
  const float* wv = (const float*)d_in[6];
  const float* wo = (const float*)d_in[7];
  float* out = (float*)d_out;

  char* ws = (char*)d_ws;
  u16* xb  = (u16*)(ws + 0);           // 4096x2048        16.78 MB
  u16* wqb = (u16*)(ws + 16777216);    // 2048x2048         8.39 MB
  u16* wkb = (u16*)(ws + 25165824);    //  512x2048         2.10 MB
  u16* wvb = (u16*)(ws + 27262976);    //  512x2048         2.10 MB
  u16* wob = (u16*)(ws + 29360128);    // 2048x2048         8.39 MB
  u16* qb  = (u16*)(ws + 37748736);    // [B,S,16,128]     16.78 MB
  u16* kb  = (u16*)(ws + 54525952);    // [B,S,4,128]       4.19 MB
  u16* vtb = (u16*)(ws + 58720256);    // [B,4,128,S]       4.19 MB
  u16* ob  = (u16*)(ws + 62914560);    // [B,S,16,128]     16.78 MB

  cvt_all<<<18432, 256, 0, stream>>>(x, wq, wk, wv, wo, xb, wqb, wkb, wvb, wob);
  gemm_qkv<<<dim3(32, 24), 256, 0, stream>>>(xb, wqb, wkb, wvb, qb, kb, vtb);
  rope_both<<<20480, 256, 0, stream>>>(qb, kb, fr);
  flash_attn<<<512, 256, 0, stream>>>(qb, kb, vtb, ob);
  gemm_out<<<dim3(32, 16), 256, 0, stream>>>(ob, wob, out);
}

// Round 6
// 304.389 us; speedup vs baseline: 1.0008x; 1.0008x over previous
//
#include <hip/hip_runtime.h>

typedef unsigned short u16;
typedef unsigned int u32;
typedef __bf16 bf16x8 __attribute__((ext_vector_type(8)));
typedef float floatx4 __attribute__((ext_vector_type(4)));

// B=4, S=1024, DIM=2048, HQ=16, HKV=4, HD=128, G=4
__device__ __forceinline__ u16 f2bf(float x) {
  union { float f; u32 u; } v; v.f = x;
  u32 r = v.u + 0x7fffu + ((v.u >> 16) & 1u);   // RNE
  return (u16)(r >> 16);
}
__device__ __forceinline__ float bf2f(u16 x) {
  union { float f; u32 u; } v; v.u = ((u32)x) << 16;
  return v.f;
}

// async global->LDS, 16B per lane. LDS dest must be wave-uniform base + lane*16.
__device__ __forceinline__ void gl_lds16(const u16* g, u16* l) {
  __builtin_amdgcn_global_load_lds((const __attribute__((address_space(1))) void*)g,
                                   (__attribute__((address_space(3))) void*)l, 16, 0, 0);
}

// ---------------- fused f32 -> bf16 conversion of all 5 tensors ----------------
__global__ __launch_bounds__(256) void cvt_all(const float* __restrict__ x,
                                               const float* __restrict__ wq,
                                               const float* __restrict__ wk,
                                               const float* __restrict__ wv,
                                               const float* __restrict__ wo,
                                               u16* __restrict__ xb, u16* __restrict__ wqb,
                                               u16* __restrict__ wkb, u16* __restrict__ wvb,
                                               u16* __restrict__ wob) {
  int i = blockIdx.x * 256 + threadIdx.x;  // float4 index
  const float* s; u16* d; int off;
  if (i < 2097152)      { s = x;  d = xb;  off = 0; }
  else if (i < 3145728) { s = wq; d = wqb; off = 2097152; }
  else if (i < 3407872) { s = wk; d = wkb; off = 3145728; }
  else if (i < 3670016) { s = wv; d = wvb; off = 3407872; }
  else                  { s = wo; d = wob; off = 3670016; }
  i -= off;
  float4 v = ((const float4*)s)[i];
  uint2 o;
  o.x = (u32)f2bf(v.x) | ((u32)f2bf(v.y) << 16);
  o.y = (u32)f2bf(v.z) | ((u32)f2bf(v.w) << 16);
  ((uint2*)d)[i] = o;
}

// ---------------- RoPE in-place on q and k in one launch ----------------
__global__ __launch_bounds__(256) void rope_both(u16* __restrict__ qb, u16* __restrict__ kb,
                                                 const float* __restrict__ fr) {
  int idx = blockIdx.x * 256 + threadIdx.x;
  u16* t; int lgH; float scale;
  if (idx < 4194304) { t = qb; lgH = 4; scale = 0.08838834764831845f; }
  else               { t = kb; lgH = 2; scale = 1.0f; idx -= 4194304; }
  int p = idx & 63;
  int bsh = idx >> 6;
  int s = (bsh >> lgH) & 1023;
  float th = fr[s * 64 + p];
  float sn, cs;
  sincosf(th, &sn, &cs);
  u32* base = (u32*)(t + (size_t)bsh * 128 + p * 2);
  u32 pr = *base;
  float e = bf2f((u16)(pr & 0xffffu));
  float o = bf2f((u16)(pr >> 16));
  u16 re = f2bf((e * cs - o * sn) * scale);
  u16 im = f2bf((e * sn + o * cs) * scale);
  *base = (u32)re | ((u32)im << 16);
}

// ---------------- shared GEMM core: 128x128 tile, K=2048, BK=64, async staging --
// LDS layout XOR-swizzled: LDS(row, chunk) holds global(row, chunk ^ (row&7)),
// chunk = 8 u16 = 16 B. Kills the 16-way ds_read_b128 bank conflicts of the
// naive row-stride-128B layout (row&7 spreads reads across all 8 chunk slots).
__device__ __forceinline__ void gemm_core(const u16* __restrict__ A, const u16* __restrict__ Bw,
                                          u16* sA, u16* sB, int m0, int n0,
                                          floatx4 acc[4][4]) {
  const int tid = threadIdx.x;
  const int wave = tid >> 6, lane = tid & 63;
  const int quad = lane >> 4, l16 = lane & 15;
  const int wm = (wave >> 1) * 64, wn = (wave & 1) * 64;
  const int srow = wave * 8 + (lane >> 3);
  // swizzled global source chunk for this lane's LDS slot (chunk = lane&7, row&7 = (lane>>3)&7)
  const int scol = (((lane & 7) ^ ((lane >> 3) & 7)) * 8);
  const int lds_off = wave * 512 + lane * 8;
  const int swA = (l16 & 7);  // read-side swizzle key (row&7 for MFMA fragment rows)
  for (int k0 = 0; k0 < 2048; k0 += 64) {
    __syncthreads();
    #pragma unroll
    for (int c = 0; c < 4; c++) {
      gl_lds16(A + (size_t)(m0 + c * 32 + srow) * 2048 + k0 + scol, sA + c * 2048 + lds_off);
      gl_lds16(Bw + (size_t)(n0 + c * 32 + srow) * 2048 + k0 + scol, sB + c * 2048 + lds_off);
    }
    __syncthreads();
    #pragma unroll
    for (int ks = 0; ks < 64; ks += 32) {
      const int pc = ((((ks >> 3) + quad) ^ swA) << 3);  // physical chunk*8
      bf16x8 af[4], bw[4];
      #pragma unroll
      for (int i = 0; i < 4; i++)
        af[i] = *(const bf16x8*)&sA[(wm + i * 16 + l16) * 64 + pc];
      #pragma unroll
      for (int j = 0; j < 4; j++)
        bw[j] = *(const bf16x8*)&sB[(wn + j * 16 + l16) * 64 + pc];
      #pragma unroll
      for (int i = 0; i < 4; i++)
        #pragma unroll
        for (int j = 0; j < 4; j++)
          acc[i][j] = __builtin_amdgcn_mfma_f32_16x16x32_bf16(af[i], bw[j], acc[i][j], 0, 0, 0);
    }
  }
}

// ---------------- fused QKV projection GEMM ----------------
__global__ __launch_bounds__(256, 2) void gemm_qkv(const u16* __restrict__ xb,
                                                   const u16* __restrict__ wqb,
                                                   const u16* __restrict__ wkb,
                                                   const u16* __restrict__ wvb,
                                                   u16* __restrict__ qb, u16* __restrict__ kb,
                                                   u16* __restrict__ vtb) {
  __shared__ __align__(16) u16 sA[128 * 64];
  __shared__ __align__(16) u16 sB[128 * 64];
  const int by = blockIdx.y;
  const u16* Bw; int n0, mode;
  if (by < 16)      { Bw = wqb; n0 = by * 128;        mode = 0; }
  else if (by < 20) { Bw = wkb; n0 = (by - 16) * 128; mode = 1; }
  else              { Bw = wvb; n0 = (by - 20) * 128; mode = 2; }
  const int m0 = blockIdx.x * 128;
  floatx4 acc[4][4] = {};
  gemm_core(xb, Bw, sA, sB, m0, n0, acc);
  const int tid = threadIdx.x;
  const int wave = tid >> 6, lane = tid & 63;
  const int quad = lane >> 4, l16 = lane & 15;
  const int wm = (wave >> 1) * 64, wn = (wave & 1) * 64;
  #pragma unroll
  for (int i = 0; i < 4; i++) {
    #pragma unroll
    for (int j = 0; j < 4; j++) {
      const int row0 = m0 + wm + i * 16 + quad * 4;
      const int col = n0 + wn + j * 16 + l16;
      #pragma unroll
      for (int r = 0; r < 4; r++) {
        int m = row0 + r;
        u16 val = f2bf(acc[i][j][r]);
        if (mode == 0) {
          qb[(size_t)m * 2048 + col] = val;
        } else if (mode == 1) {
          kb[(size_t)m * 512 + col] = val;
        } else {
          int b = m >> 10, sI = m & 1023, kvh = col >> 7, hd = col & 127;
          vtb[((size_t)((b * 4 + kvh) * 128 + hd)) * 1024 + sI] = val;
        }
      }
    }
  }
}

// ---------------- output projection GEMM (fp32 out) ----------------
__global__ __launch_bounds__(256, 2) void gemm_out(const u16* __restrict__ ob,
                                                   const u16* __restrict__ wob,
                                                   float* __restrict__ Cf) {
  __shared__ __align__(16) u16 sA[128 * 64];
  __shared__ __align__(16) u16 sB[128 * 64];
  const int m0 = blockIdx.x * 128, n0 = blockIdx.y * 128;
  floatx4 acc[4][4] = {};
  gemm_core(ob, wob, sA, sB, m0, n0, acc);
  const int tid = threadIdx.x;
  const int wave = tid >> 6, lane = tid & 63;
  const int quad = lane >> 4, l16 = lane & 15;
  const int wm = (wave >> 1) * 64, wn = (wave & 1) * 64;
  #pragma unroll
  for (int i = 0; i < 4; i++) {
    #pragma unroll
    for (int j = 0; j < 4; j++) {
      const int row0 = m0 + wm + i * 16 + quad * 4;
      const int col = n0 + wn + j * 16 + l16;
      #pragma unroll
      for (int r = 0; r < 4; r++)
        Cf[(size_t)(row0 + r) * 2048 + col] = acc[i][j][r];
    }
  }
}

// ---------------- flash attention (no-max softmax, S^T form, paired balance) ----
// Per-tile software pipeline: K 1-deep ping-pong prefetch; V half 0 issued before
// QK, half 1 after QK. amdgpu_waves_per_eu(2,2) clamps occupancy to the level we
// already have (LDS-capped 2 blocks/CU) -> 256-VGPR budget, so all ~32 loads/tile
// stay in flight instead of being serialized through a 128-reg recycle.
__device__ __forceinline__ void attn_chunk(const u16* __restrict__ qbaseHead,
                                           const u16* __restrict__ kbase,
                                           const u16* __restrict__ vbase,
                                           int qr0, int kt_begin, int kt_end,
                                           u16* myP, floatx4 (&o_acc)[2][8],
                                           float (&l_part)[2], int quad, int l16) {
  const floatx4 vzero = {0.f, 0.f, 0.f, 0.f};
  #pragma unroll
  for (int i = 0; i < 2; i++) {
    l_part[i] = 0.f;
    #pragma unroll
    for (int j = 0; j < 8; j++) o_acc[i][j] = vzero;
  }
  // Q B-fragments in registers: rows qr0+i*16+l16, k = ks*32+quad*8
  bf16x8 aq[2][4];
  #pragma unroll
  for (int i = 0; i < 2; i++)
    #pragma unroll
    for (int ks = 0; ks < 4; ks++)
      aq[i][ks] = *(const bf16x8*)(qbaseHead + (size_t)(qr0 + i * 16 + l16) * 2048 + ks * 32 + quad * 8);

  // K pipeline prologue: slice (kt_begin, ks=0) into bk[0]
  bf16x8 bk[2][4];
  #pragma unroll
  for (int j = 0; j < 4; j++)
    bk[0][j] = *(const bf16x8*)(kbase + (size_t)(kt_begin * 64 + j * 16 + l16) * 512 + quad * 8);

  for (int kt = kt_begin; kt < kt_end; kt++) {
    const int t0 = kt * 64;
    const int t0n = (kt + 1 < kt_end) ? t0 + 64 : t0;  // clamp: last-iter prefetch unused
    floatx4 s_acc[4][2];
    #pragma unroll
    for (int j = 0; j < 4; j++)
      #pragma unroll
      for (int i = 0; i < 2; i++) s_acc[j][i] = vzero;
    // V half 0 in flight during QK
    bf16x8 bv[2][8];
    #pragma unroll
    for (int j2 = 0; j2 < 8; j2++)
      bv[0][j2] = *(const bf16x8*)(vbase + (size_t)(j2 * 16 + l16) * 1024 + t0 + quad * 8);
    // ---- S^T = K Q^T with 1-deep K prefetch ----
    #pragma unroll
    for (int ks = 0; ks < 4; ks++) {
      const int nks = (ks + 1) & 3;
      const int nt0 = (ks == 3) ? t0n : t0;
      #pragma unroll
      for (int j = 0; j < 4; j++)
        bk[(ks + 1) & 1][j] =
            *(const bf16x8*)(kbase + (size_t)(nt0 + j * 16 + l16) * 512 + nks * 32 + quad * 8);
      #pragma unroll
      for (int j = 0; j < 4; j++)
        #pragma unroll
        for (int i = 0; i < 2; i++)
          s_acc[j][i] = __builtin_amdgcn_mfma_f32_16x16x32_bf16(bk[ks & 1][j], aq[i][ks], s_acc[j][i], 0, 0, 0);
    }
    // V half 1 in flight during softmax
    #pragma unroll
    for (int j2 = 0; j2 < 8; j2++)
      bv[1][j2] = *(const bf16x8*)(vbase + (size_t)(j2 * 16 + l16) * 1024 + t0 + 32 + quad * 8);
    // ---- no-max softmax: p = exp(s) (scale folded into Q), causal mask ----
    // lane holds qrow = qr0+i*16+l16, keys t0+j*16+quad*4+{0..3}
    #pragma unroll
    for (int i = 0; i < 2; i++) {
      const int qrow = qr0 + i * 16 + l16;
      #pragma unroll
      for (int j = 0; j < 4; j++) {
        const int key0 = t0 + j * 16 + quad * 4;
        float e0 = (key0 + 0 <= qrow) ? __expf(s_acc[j][i][0]) : 0.f;
        float e1 = (key0 + 1 <= qrow) ? __expf(s_acc[j][i][1]) : 0.f;
        float e2 = (key0 + 2 <= qrow) ? __expf(s_acc[j][i][2]) : 0.f;
        float e3 = (key0 + 3 <= qrow) ? __expf(s_acc[j][i][3]) : 0.f;
        l_part[i] += (e0 + e1) + (e2 + e3);
        uint2 w;
        w.x = (u32)f2bf(e0) | ((u32)f2bf(e1) << 16);
        w.y = (u32)f2bf(e2) | ((u32)f2bf(e3) << 16);
        *(uint2*)&myP[(i * 16 + l16) * 68 + j * 16 + quad * 4] = w;  // ds_write_b64
      }
    }
    // ---- O += P V : A = P[qrow][key] (b128 reads), B = V^T rows ----
    #pragma unroll
    for (int ks2 = 0; ks2 < 2; ks2++) {
      bf16x8 ap[2];
      #pragma unroll
      for (int i = 0; i < 2; i++)
        ap[i] = *(const bf16x8*)&myP[(i * 16 + l16) * 68 + ks2 * 32 + quad * 8];
      #pragma unroll
      for (int i = 0; i < 2; i++)
        #pragma unroll
        for (int j2 = 0; j2 < 8; j2++)
          o_acc[i][j2] = __builtin_amdgcn_mfma_f32_16x16x32_bf16(ap[i], bv[ks2][j2], o_acc[i][j2], 0, 0, 0);
    }
  }
}

__device__ __forceinline__ void store_out(u16* __restrict__ obaseHead, int qr0,
                                          floatx4 (&o_acc)[2][8], float (&l_part)[2],
                                          int quad, int l16) {
  #pragma unroll
  for (int i = 0; i < 2; i++) {
    float lr = l_part[i];
    lr += __shfl_xor(lr, 16);
    lr += __shfl_xor(lr, 32);
    // lane with l16=x (quad 0) now holds row total for qrow i*16+x
    #pragma unroll
    for (int r = 0; r < 4; r++) {
      const float inv = 1.f / __shfl(lr, quad * 4 + r);
      const int row = qr0 + i * 16 + quad * 4 + r;
      #pragma unroll
      for (int j = 0; j < 8; j++)
        obaseHead[(size_t)row * 2048 + j * 16 + l16] = f2bf(o_acc[i][j][r] * inv);
    }
  }
}

// grid 512: head = bi&63 (XCD-local K/V), sub = bi>>6; 4 waves = 2 (A,B) pairs.
// Pair pr handles chunks (p, 31-p); A computes first tA key-tiles of long chunk,
// B computes short chunk fully + rest of long chunk; partials are additive
// (no-max softmax) -> combine via LDS.
__global__ __launch_bounds__(256)
__attribute__((amdgpu_waves_per_eu(2, 2)))
void flash_attn(const u16* __restrict__ q,
                const u16* __restrict__ k,
                const u16* __restrict__ vt,
                u16* __restrict__ o) {
  __shared__ __align__(16) char smem[52224];  // 4*4352 P + 2*(16896 O + 512 L)
  const int tid = threadIdx.x;
  const int wave = tid >> 6, lane = tid & 63;
  const int quad = lane >> 4, l16 = lane & 15;
  const int pr = wave >> 1, role = wave & 1;  // role 0 = A (partial), 1 = B
  const int bi = blockIdx.x;
  const int h = bi & 63;                      // b*16 + hq
  const int b = h >> 4, hq = h & 15, kv = (hq >> 2);
  const int pair = (bi >> 6) * 2 + pr;        // 0..15
  const int p = pair, qc = 31 - pair;
  const int Tp = (32 * p + 31) / 64 + 1, Tq = (32 * qc + 31) / 64 + 1;
  const int tA = (Tp + Tq) >> 1;
  u16* myP = (u16*)(smem + wave * 4352);
  float* ldsO = (float*)(smem + 17408 + pr * 17408);
  float* ldsL = (float*)(smem + 17408 + pr * 17408 + 16896);

  const u16* qbaseHead = q + (size_t)b * 2097152 + hq * 128;
  const u16* kbase = k + (size_t)b * 524288 + kv * 128;
  const u16* vbase = vt + (size_t)(b * 4 + kv) * 131072;
  u16* obaseHead = o + (size_t)b * 2097152 + hq * 128;

  floatx4 o_acc[2][8];
  float l_part[2];
  if (role == 0) {
    attn_chunk(qbaseHead, kbase, vbase, qc * 32, 0, tA, myP, o_acc, l_part, quad, l16);
    #pragma unroll
    for (int i = 0; i < 2; i++) {
      ldsL[i * 64 + lane] = l_part[i];
      #pragma unroll
      for (int j = 0; j < 8; j++)
        #pragma unroll
        for (int r = 0; r < 4; r++)
          ldsO[(i * 16 + quad * 4 + r) * 132 + j * 16 + l16] = o_acc[i][j][r];
    }
    __syncthreads();
  } else {
    attn_chunk(qbaseHead, kbase, vbase, p * 32, 0, Tp, myP, o_acc, l_part, quad, l16);
    store_out(obaseHead, p * 32, o_acc, l_part, quad, l16);
    attn_chunk(qbaseHead, kbase, vbase, qc * 32, tA, Tq, myP, o_acc, l_part, quad, l16);
    __syncthreads();
    #pragma unroll
    for (int i = 0; i < 2; i++) {
      l_part[i] += ldsL[i * 64 + lane];
      #pragma unroll
      for (int j = 0; j < 8; j++)
        #pragma unroll
        for (int r = 0; r < 4; r++)
          o_acc[i][j][r] += ldsO[(i * 16 + quad * 4 + r) * 132 + j * 16 + l16];
    }
    store_out(obaseHead, qc * 32, o_acc, l_part, quad, l16);
  }
}

extern "C" void kernel_launch(void* const* d_in, const int* in_sizes, int n_in,
                              void* d_out, int out_size, void* d_ws, size_t ws_size,
                              hipStream_t stream) {
  const float* x  = (const float*)d_in[0];
  const float* fr = (const float*)d_in[2];
  const float* wq = (const float*)d_in[4];
  const float* wk = (const float*)d_in[5];
  const float* wv = (const float*)d_in[6];
  const float* wo = (const float*)d_in[7];
  float* out = (float*)d_out;

  char* ws = (char*)d_ws;
  u16* xb  = (u16*)(ws + 0);           // 4096x2048        16.78 MB
  u16* wqb = (u16*)(ws + 16777216);    // 2048x2048         8.39 MB
  u16* wkb = (u16*)(ws + 25165824);    //  512x2048         2.10 MB
  u16* wvb = (u16*)(ws + 27262976);    //  512x2048         2.10 MB
  u16* wob = (u16*)(ws + 29360128);    // 2048x2048         8.39 MB
  u16* qb  = (u16*)(ws + 37748736);    // [B,S,16,128]     16.78 MB
  u16* kb  = (u16*)(ws + 54525952);    // [B,S,4,128]       4.19 MB
  u16* vtb = (u16*)(ws + 58720256);    // [B,4,128,S]       4.19 MB
  u16* ob  = (u16*)(ws + 62914560);    // [B,S,16,128]     16.78 MB

  cvt_all<<<18432, 256, 0, stream>>>(x, wq, wk, wv, wo, xb, wqb, wkb, wvb, wob);
  gemm_qkv<<<dim3(32, 24), 256, 0, stream>>>(xb, wqb, wkb, wvb, qb, kb, vtb);
  rope_both<<<20480, 256, 0, stream>>>(qb, kb, fr);
  flash_attn<<<512, 256, 0, stream>>>(qb, kb, vtb, ob);
  gemm_out<<<dim3(32, 16), 256, 0, stream>>>(ob, wob, out);
}